// Round 6
// baseline (438.345 us; speedup 1.0000x reference)
//
#include <hip/hip_runtime.h>

#define N_NODES 100000
#define N_EDGES 1250000
#define D 64

#define SCAN_TPB 256
#define SCAN_ELEMS 1024
#define SCAN_NB ((N_NODES + SCAN_ELEMS - 1) / SCAN_ELEMS)   // 98

// ---- bf16 helpers (finite values only) ----
__device__ inline unsigned short f2bf(float f) {
    unsigned int u = __float_as_uint(f);
    unsigned int r = (u + 0x7fffu + ((u >> 16) & 1u)) >> 16;
    return (unsigned short)r;
}
__device__ inline float4 unpack_bf4(uint2 u) {
    float4 f;
    f.x = __uint_as_float(u.x << 16);
    f.y = __uint_as_float(u.x & 0xffff0000u);
    f.z = __uint_as_float(u.y << 16);
    f.w = __uint_as_float(u.y & 0xffff0000u);
    return f;
}

// ---------------- x fp32 -> bf16, fused with hist zeroing ----------------
__global__ __launch_bounds__(256)
void convert_zero_kernel(const float4* __restrict__ xin, ushort4* __restrict__ xb,
                         int n4, int4* __restrict__ hist4, int nh4) {
    int i = blockIdx.x * 256 + threadIdx.x;
    if (i < n4) {
        float4 v = xin[i];
        ushort4 u;
        u.x = f2bf(v.x); u.y = f2bf(v.y); u.z = f2bf(v.z); u.w = f2bf(v.w);
        xb[i] = u;
    }
    if (i < nh4) hist4[i] = make_int4(0, 0, 0, 0);
}

// ---------------- degree histogram (8 edges/thread) ----------------
__global__ __launch_bounds__(256)
void hist_kernel(const int4* __restrict__ dst4, int* __restrict__ hist) {
    int i = blockIdx.x * 256 + threadIdx.x;
    if (i < N_EDGES / 8) {
        int4 a = dst4[2 * i];
        int4 b = dst4[2 * i + 1];
        atomicAdd(&hist[a.x], 1);
        atomicAdd(&hist[a.y], 1);
        atomicAdd(&hist[a.z], 1);
        atomicAdd(&hist[a.w], 1);
        atomicAdd(&hist[b.x], 1);
        atomicAdd(&hist[b.y], 1);
        atomicAdd(&hist[b.z], 1);
        atomicAdd(&hist[b.w], 1);
    }
}

// ---------------- scan step 1: per-block reduce ----------------
__global__ __launch_bounds__(SCAN_TPB)
void scan_reduce_kernel(const int* __restrict__ hist, int* __restrict__ partials) {
    __shared__ int sdata[SCAN_TPB];
    int t = threadIdx.x;
    int base = blockIdx.x * SCAN_ELEMS + t * 4;
    int s = 0;
#pragma unroll
    for (int k = 0; k < 4; ++k) {
        int i = base + k;
        if (i < N_NODES) s += hist[i];
    }
    sdata[t] = s;
    __syncthreads();
    for (int off = SCAN_TPB / 2; off > 0; off >>= 1) {
        if (t < off) sdata[t] += sdata[t + off];
        __syncthreads();
    }
    if (t == 0) partials[blockIdx.x] = sdata[0];
}

// ---------------- scan step 2: exclusive scan of partials (1 block) ----------------
__global__ __launch_bounds__(128)
void scan_partials_kernel(int* __restrict__ partials) {
    __shared__ int s[128];
    int t = threadIdx.x;
    int v = (t < SCAN_NB) ? partials[t] : 0;
    s[t] = v;
    __syncthreads();
    for (int off = 1; off < 128; off <<= 1) {
        int x = (t >= off) ? s[t - off] : 0;
        __syncthreads();
        s[t] += x;
        __syncthreads();
    }
    if (t < SCAN_NB) partials[t] = (t == 0) ? 0 : s[t - 1];
}

// ---------------- scan step 3: write exclusive prefix -> cursor ----------------
__global__ __launch_bounds__(SCAN_TPB)
void scan_write_kernel(const int* __restrict__ hist, const int* __restrict__ partials,
                       int* __restrict__ cursor) {
    __shared__ int sdata[SCAN_TPB];
    int t = threadIdx.x;
    int base = blockIdx.x * SCAN_ELEMS + t * 4;
    int h[4];
    int tot = 0;
#pragma unroll
    for (int k = 0; k < 4; ++k) {
        int i = base + k;
        h[k] = (i < N_NODES) ? hist[i] : 0;
        tot += h[k];
    }
    sdata[t] = tot;
    __syncthreads();
    for (int off = 1; off < SCAN_TPB; off <<= 1) {
        int x = (t >= off) ? sdata[t - off] : 0;
        __syncthreads();
        sdata[t] += x;
        __syncthreads();
    }
    int run = partials[blockIdx.x] + sdata[t] - tot;   // exclusive thread prefix
#pragma unroll
    for (int k = 0; k < 4; ++k) {
        int i = base + k;
        if (i < N_NODES) { cursor[i] = run; run += h[k]; }
    }
}

// ---------------- bucket: counting-sort srcs by dst (8 edges/thread) ----------------
__global__ __launch_bounds__(256)
void bucket_kernel(const int4* __restrict__ src4, const int4* __restrict__ dst4,
                   int* __restrict__ cursor, int* __restrict__ sorted_src) {
    int i = blockIdx.x * 256 + threadIdx.x;
    if (i < N_EDGES / 8) {
        int4 s0 = src4[2 * i];
        int4 s1 = src4[2 * i + 1];
        int4 d0 = dst4[2 * i];
        int4 d1 = dst4[2 * i + 1];
        sorted_src[atomicAdd(&cursor[d0.x], 1)] = s0.x;
        sorted_src[atomicAdd(&cursor[d0.y], 1)] = s0.y;
        sorted_src[atomicAdd(&cursor[d0.z], 1)] = s0.z;
        sorted_src[atomicAdd(&cursor[d0.w], 1)] = s0.w;
        sorted_src[atomicAdd(&cursor[d1.x], 1)] = s1.x;
        sorted_src[atomicAdd(&cursor[d1.y], 1)] = s1.y;
        sorted_src[atomicAdd(&cursor[d1.z], 1)] = s1.z;
        sorted_src[atomicAdd(&cursor[d1.w], 1)] = s1.w;
    }
}

// ---------------- fused layer: gather-mean + (mean@Wl + b + x@Wr) ----------------
// bf16 input. Quad-edge gather: uint2 (4 bf16) per lane, 16 lanes/row,
// lane quarter q handles edge 4t+q (selected via one ds_bpermute shfl).
// Cross-quarter combine: shfl_xor(16) + shfl_xor(32). 17.4 KB LDS, 8 blocks/CU.
template <typename TOUT>
__global__ __launch_bounds__(256, 8)
void fused_layer_kernel(const unsigned short* __restrict__ xin,   // bf16 [N,D]
                        const int* __restrict__ cursor_end,
                        const int* __restrict__ deg,
                        const int* __restrict__ sorted_src,
                        const float* __restrict__ Wl,
                        const float* __restrict__ bl,
                        const float* __restrict__ Wr,
                        TOUT* __restrict__ out,
                        int relu) {
    __shared__ float sM[32][68];
    __shared__ float sX[32][68];

    const uint2* __restrict__ xin64 = (const uint2*)xin;   // row = 16 uint2

    const int tid = threadIdx.x;
    const int row0 = blockIdx.x * 32;

    const int wave = tid >> 6;
    const int lane = tid & 63;
    const int q  = lane >> 4;        // quarter: handles edges 4t+q
    const int f2 = lane & 15;        // uint2 index within row (features f2*4..f2*4+3)

    for (int r = wave; r < 32; r += 4) {
        int n = row0 + r;            // grid is exactly N_NODES/32 -> n < N_NODES
        float4 a = make_float4(0.f, 0.f, 0.f, 0.f);
        int dg = deg[n];
        int st = cursor_end[n] - dg;
        float4 xv = unpack_bf4(xin64[(size_t)n * 16 + f2]);

        for (int base = 0; base < dg; base += 64) {
            int m = dg - base; if (m > 64) m = 64;
            int idx = 0;
            if (lane < m) idx = sorted_src[st + base + lane];
            int quads = m >> 2;
            float4 acc0 = make_float4(0.f, 0.f, 0.f, 0.f);
            float4 acc1 = make_float4(0.f, 0.f, 0.f, 0.f);
            int t = 0;
            for (; t + 2 <= quads; t += 2) {
                int sA = __shfl(idx, 4 * t + q);
                int sB = __shfl(idx, 4 * t + 4 + q);
                float4 fA = unpack_bf4(xin64[(size_t)sA * 16 + f2]);
                float4 fB = unpack_bf4(xin64[(size_t)sB * 16 + f2]);
                acc0.x += fA.x; acc0.y += fA.y; acc0.z += fA.z; acc0.w += fA.w;
                acc1.x += fB.x; acc1.y += fB.y; acc1.z += fB.z; acc1.w += fB.w;
            }
            if (t < quads) {
                int sA = __shfl(idx, 4 * t + q);
                float4 fA = unpack_bf4(xin64[(size_t)sA * 16 + f2]);
                acc0.x += fA.x; acc0.y += fA.y; acc0.z += fA.z; acc0.w += fA.w;
            }
            // tail (<=3 edges): quarter 0 only
            for (int e = quads * 4; e < m; ++e) {
                int s = __builtin_amdgcn_readlane(idx, e);
                if (q == 0) {
                    float4 f = unpack_bf4(xin64[(size_t)s * 16 + f2]);
                    acc1.x += f.x; acc1.y += f.y; acc1.z += f.z; acc1.w += f.w;
                }
            }
            a.x += acc0.x + acc1.x; a.y += acc0.y + acc1.y;
            a.z += acc0.z + acc1.z; a.w += acc0.w + acc1.w;
        }

        // combine quarters: lanes l, l+16, l+32, l+48 hold same features
        a.x += __shfl_xor(a.x, 16); a.y += __shfl_xor(a.y, 16);
        a.z += __shfl_xor(a.z, 16); a.w += __shfl_xor(a.w, 16);
        a.x += __shfl_xor(a.x, 32); a.y += __shfl_xor(a.y, 32);
        a.z += __shfl_xor(a.z, 32); a.w += __shfl_xor(a.w, 32);

        float inv = 1.0f / (float)(dg > 0 ? dg : 1);
        if (q == 0) {
            *(float4*)&sM[r][f2 * 4] =
                make_float4(a.x * inv, a.y * inv, a.z * inv, a.w * inv);
            *(float4*)&sX[r][f2 * 4] = xv;
        }
    }
    __syncthreads();

    // GEMM phase: thread = 2 rows x 4 cols; W read from global (L1/L2 resident)
    const int tx = tid & 15, ty = tid >> 4;   // ty 0..15
    const int j0 = tx * 4;
    const int i0 = ty * 2;

    float acc[2][4];
    float4 b4 = *(const float4*)&bl[j0];
#pragma unroll
    for (int i = 0; i < 2; ++i) {
        acc[i][0] = b4.x; acc[i][1] = b4.y; acc[i][2] = b4.z; acc[i][3] = b4.w;
    }

    for (int k = 0; k < 64; k += 4) {
        float4 wl[4], wr[4];
#pragma unroll
        for (int kk = 0; kk < 4; ++kk) {
            wl[kk] = *(const float4*)&Wl[(k + kk) * D + j0];
            wr[kk] = *(const float4*)&Wr[(k + kk) * D + j0];
        }
#pragma unroll
        for (int i = 0; i < 2; ++i) {
            float4 m  = *(const float4*)&sM[i0 + i][k];
            float4 xv = *(const float4*)&sX[i0 + i][k];
            float mk[4] = {m.x, m.y, m.z, m.w};
            float xk[4] = {xv.x, xv.y, xv.z, xv.w};
#pragma unroll
            for (int kk = 0; kk < 4; ++kk) {
                acc[i][0] += mk[kk] * wl[kk].x + xk[kk] * wr[kk].x;
                acc[i][1] += mk[kk] * wl[kk].y + xk[kk] * wr[kk].y;
                acc[i][2] += mk[kk] * wl[kk].z + xk[kk] * wr[kk].z;
                acc[i][3] += mk[kk] * wl[kk].w + xk[kk] * wr[kk].w;
            }
        }
    }

#pragma unroll
    for (int i = 0; i < 2; ++i) {
        int n = row0 + i0 + i;
        if (n < N_NODES) {
            float o[4];
#pragma unroll
            for (int j = 0; j < 4; ++j)
                o[j] = relu ? fmaxf(acc[i][j], 0.f) : acc[i][j];
            if constexpr (__hip_internal::is_same<TOUT, unsigned short>::value) {
                ushort4 u;
                u.x = f2bf(o[0]); u.y = f2bf(o[1]); u.z = f2bf(o[2]); u.w = f2bf(o[3]);
                *(ushort4*)&out[(size_t)n * D + j0] = u;
            } else {
                float4 f;
                f.x = o[0]; f.y = o[1]; f.z = o[2]; f.w = o[3];
                *(float4*)&out[(size_t)n * D + j0] = f;
            }
        }
    }
}

extern "C" void kernel_launch(void* const* d_in, const int* in_sizes, int n_in,
                              void* d_out, int out_size, void* d_ws, size_t ws_size,
                              hipStream_t stream) {
    const float* x   = (const float*)d_in[0];
    const int*   ei  = (const int*)d_in[1];
    const float* Wl1 = (const float*)d_in[2];
    const float* b1  = (const float*)d_in[3];
    const float* Wr1 = (const float*)d_in[4];
    const float* Wl2 = (const float*)d_in[5];
    const float* b2  = (const float*)d_in[6];
    const float* Wr2 = (const float*)d_in[7];

    const int* src = ei;
    const int* dst = ei + N_EDGES;

    // ws layout (ints): hist[100000] | cursor[100000] | partials[128] | sorted_src[1250000] | h_bf16
    int* hist       = (int*)d_ws;
    int* cursor     = hist + N_NODES;
    int* partials   = cursor + N_NODES;
    int* sorted_src = partials + 128;
    unsigned short* h = (unsigned short*)(sorted_src + N_EDGES);   // [N, D] bf16
    float* out = (float*)d_out;
    // xb (bf16 x) lives in d_out: dead until layer 2 fully rewrites d_out from h.
    unsigned short* xb = (unsigned short*)d_out;

    const int edge8_blocks = (N_EDGES / 8 + 255) / 256;
    const int dense_blocks = N_NODES / 32;   // exactly 3125
    const int conv4 = N_NODES * D / 4;

    // x -> bf16 (into d_out scratch) + zero hist, one kernel
    convert_zero_kernel<<<(conv4 + 255) / 256, 256, 0, stream>>>(
        (const float4*)x, (ushort4*)xb, conv4, (int4*)hist, N_NODES / 4);

    // build CSR (dst-sorted srcs)
    hist_kernel<<<edge8_blocks, 256, 0, stream>>>((const int4*)dst, hist);
    scan_reduce_kernel<<<SCAN_NB, SCAN_TPB, 0, stream>>>(hist, partials);
    scan_partials_kernel<<<1, 128, 0, stream>>>(partials);
    scan_write_kernel<<<SCAN_NB, SCAN_TPB, 0, stream>>>(hist, partials, cursor);
    bucket_kernel<<<edge8_blocks, 256, 0, stream>>>((const int4*)src, (const int4*)dst,
                                                    cursor, sorted_src);

    // layer 1: xb (bf16, in d_out) -> h (bf16, ws)
    fused_layer_kernel<unsigned short><<<dense_blocks, 256, 0, stream>>>(
        xb, cursor, hist, sorted_src, Wl1, b1, Wr1, h, /*relu=*/1);
    // layer 2: h (bf16) -> out (fp32, d_out) — overwrites xb entirely
    fused_layer_kernel<float><<<dense_blocks, 256, 0, stream>>>(
        h, cursor, hist, sorted_src, Wl2, b2, Wr2, out, /*relu=*/0);
}